// Round 1
// baseline (698.447 us; speedup 1.0000x reference)
//
#include <hip/hip_runtime.h>
#include <hip/hip_bf16.h>

typedef unsigned short u16;
typedef __attribute__((ext_vector_type(8))) short bf16x8;
typedef __attribute__((ext_vector_type(4))) float f32x4;

#define DEVINL __device__ __forceinline__

DEVINL u16 f2b(float f) {
    __hip_bfloat16 h = __float2bfloat16(f);
    return __builtin_bit_cast(u16, h);
}
DEVINL float b2f(u16 u) {
    unsigned int x = ((unsigned int)u) << 16;
    return __builtin_bit_cast(float, x);
}
DEVINL int iabs(int x) { return x < 0 ? -x : x; }

#define GL2LDS(g, s)                                                                     \
    __builtin_amdgcn_global_load_lds(                                                    \
        (const __attribute__((address_space(1))) unsigned int*)(g),                      \
        (__attribute__((address_space(3))) unsigned int*)(s), 16, 0, 0)

// ---------------------------------------------------------------------------
// Weight convert + transpose: w[k][n] f32 -> wt[n][k] bf16
// grid (32, 32, 4), block 256. z: 0=wq,1=wk,2=wv -> wqkvt rows z*1024.. ; 3=wo -> wot
// ---------------------------------------------------------------------------
__global__ __launch_bounds__(256) void wconv_kernel(const float* __restrict__ wq,
                                                    const float* __restrict__ wk,
                                                    const float* __restrict__ wv,
                                                    const float* __restrict__ wo,
                                                    u16* __restrict__ wqkvt,
                                                    u16* __restrict__ wot) {
    __shared__ float tile[32][33];
    int z = blockIdx.z;
    const float* src = (z == 0) ? wq : (z == 1) ? wk : (z == 2) ? wv : wo;
    int n0 = blockIdx.x * 32, k0 = blockIdx.y * 32;
    int r0 = threadIdx.x >> 5, c = threadIdx.x & 31;
#pragma unroll
    for (int i = 0; i < 4; i++) {
        int r = r0 + i * 8;
        tile[r][c] = src[(size_t)(k0 + r) * 1024 + n0 + c];
    }
    __syncthreads();
    u16* dst = (z < 3) ? (wqkvt + (size_t)z * 1024 * 1024) : wot;
#pragma unroll
    for (int i = 0; i < 4; i++) {
        int r = r0 + i * 8;
        dst[(size_t)(n0 + r) * 1024 + k0 + c] = f2b(tile[c][r]);
    }
}

// ---------------------------------------------------------------------------
// LayerNorm: one wave per 1024-elem row, output bf16
// grid 14336, block 256 (4 waves)
// ---------------------------------------------------------------------------
__global__ __launch_bounds__(256) void ln_kernel(const float* __restrict__ x,
                                                 const float* __restrict__ gamma,
                                                 const float* __restrict__ beta,
                                                 u16* __restrict__ h) {
    int w = threadIdx.x >> 6, l = threadIdx.x & 63;
    size_t row = (size_t)blockIdx.x * 4 + w;
    const float4* xr = (const float4*)(x + row * 1024);
    float4 v[4];
    float s = 0.f, sq = 0.f;
#pragma unroll
    for (int i = 0; i < 4; i++) {
        v[i] = xr[l + i * 64];
        s += v[i].x + v[i].y + v[i].z + v[i].w;
        sq += v[i].x * v[i].x + v[i].y * v[i].y + v[i].z * v[i].z + v[i].w * v[i].w;
    }
#pragma unroll
    for (int off = 1; off < 64; off <<= 1) {
        s += __shfl_xor(s, off);
        sq += __shfl_xor(sq, off);
    }
    float mu = s * (1.f / 1024.f);
    float var = sq * (1.f / 1024.f) - mu * mu;
    float rstd = rsqrtf(var + 1e-5f);
    const float4* g4 = (const float4*)gamma;
    const float4* b4 = (const float4*)beta;
#pragma unroll
    for (int i = 0; i < 4; i++) {
        float4 g = g4[l + i * 64], b = b4[l + i * 64];
        float y0 = (v[i].x - mu) * rstd * g.x + b.x;
        float y1 = (v[i].y - mu) * rstd * g.y + b.y;
        float y2 = (v[i].z - mu) * rstd * g.z + b.z;
        float y3 = (v[i].w - mu) * rstd * g.w + b.w;
        unsigned int lo = (unsigned int)f2b(y0) | ((unsigned int)f2b(y1) << 16);
        unsigned int hi = (unsigned int)f2b(y2) | ((unsigned int)f2b(y3) << 16);
        uint2 pk;
        pk.x = lo;
        pk.y = hi;
        *(uint2*)(h + row * 1024 + (size_t)(l + i * 64) * 4) = pk;
    }
}

// ---------------------------------------------------------------------------
// GEMM: C[M,N] = A[M,K=1024] bf16 (row-major, stride lda) x Bt[N,1024] bf16
// 128x128 tile, BK=64, 256 threads (2x2 waves, 4x4 16x16 frags each).
// global_load_lds 16B staging, XOR-swizzled LDS via pre-swizzled global source.
// OUT_BF16: write bf16 to C (stride ldc). RESID: fp32 out += bf16 resid (stride 1024).
// M fixed 57344 (448 row-blocks). grid = 448 * (N/128).
// ---------------------------------------------------------------------------
template <int OUT_BF16, int RESID>
__global__ __launch_bounds__(256, 2) void gemm_bt(const u16* __restrict__ A,
                                                  const u16* __restrict__ Bt,
                                                  void* __restrict__ Cv,
                                                  const u16* __restrict__ resid,
                                                  int lda, int ldc) {
    __shared__ u16 smem[16384];  // A: bytes [0,16384), B: [16384,32768)
    int t = threadIdx.x;

    // XCD-chunked swizzle (nwg % 8 == 0 for both uses), then (sn, bm, bn) with
    // bn-supergroups of 8 so consecutive blocks share the A panel + a 2MB B window.
    int nwg = gridDim.x;
    int cpx = nwg >> 3;
    int wg = (blockIdx.x & 7) * cpx + (blockIdx.x >> 3);
    const int sgrp = 448 * 8;
    int sn = wg / sgrp;
    int rem = wg - sn * sgrp;
    int bm = rem >> 3;
    int bn = sn * 8 + (rem & 7);

    const char* Ab = (const char*)A;
    const char* Bb = (const char*)Bt;
    size_t aoffg[4], boffg[4];
#pragma unroll
    for (int i = 0; i < 4; i++) {
        int p = t * 16 + i * 4096;           // physical byte offset in tile
        int row = p >> 7;                    // 128B (=64 bf16) rows
        int colb = (p & 127) ^ ((row & 7) << 4);  // inverse-swizzled logical col byte
        aoffg[i] = (size_t)(bm * 128 + row) * (size_t)lda * 2 + colb;
        boffg[i] = (size_t)(bn * 128 + row) * 2048 + colb;
    }
    char* sA = (char*)smem;
    char* sB = sA + 16384;

    int l = t & 63, w = t >> 6;
    int wm = w >> 1, wn = w & 1, g = l >> 4, lr = l & 15;
    int swz = (lr & 7) << 4;

    f32x4 acc[4][4];
#pragma unroll
    for (int m = 0; m < 4; m++)
#pragma unroll
        for (int n = 0; n < 4; n++) acc[m][n] = {0.f, 0.f, 0.f, 0.f};

    for (int kt = 0; kt < 16; ++kt) {
        int kb = kt * 128;
#pragma unroll
        for (int i = 0; i < 4; i++) GL2LDS(Ab + aoffg[i] + kb, sA + i * 4096 + t * 16);
#pragma unroll
        for (int i = 0; i < 4; i++) GL2LDS(Bb + boffg[i] + kb, sB + i * 4096 + t * 16);
        __syncthreads();
#pragma unroll
        for (int ks = 0; ks < 2; ++ks) {
            bf16x8 af[4], bfv[4];
#pragma unroll
            for (int m = 0; m < 4; m++)
                af[m] = *(const bf16x8*)(sA + (wm * 64 + m * 16 + lr) * 128 +
                                         ((ks * 64 + g * 16) ^ swz));
#pragma unroll
            for (int n = 0; n < 4; n++)
                bfv[n] = *(const bf16x8*)(sB + (wn * 64 + n * 16 + lr) * 128 +
                                          ((ks * 64 + g * 16) ^ swz));
#pragma unroll
            for (int m = 0; m < 4; m++)
#pragma unroll
                for (int n = 0; n < 4; n++)
                    acc[m][n] =
                        __builtin_amdgcn_mfma_f32_16x16x32_bf16(af[m], bfv[n], acc[m][n], 0, 0, 0);
        }
        __syncthreads();
    }

    size_t row0 = (size_t)bm * 128 + wm * 64;
    int col0 = bn * 128 + wn * 64;
    if (OUT_BF16) {
        u16* C = (u16*)Cv;
#pragma unroll
        for (int m = 0; m < 4; m++)
#pragma unroll
            for (int n = 0; n < 4; n++)
#pragma unroll
                for (int r = 0; r < 4; r++) {
                    size_t rr = row0 + m * 16 + g * 4 + r;
                    int cc = col0 + n * 16 + lr;
                    C[rr * (size_t)ldc + cc] = f2b(acc[m][n][r]);
                }
    } else {
        float* C = (float*)Cv;
#pragma unroll
        for (int m = 0; m < 4; m++)
#pragma unroll
            for (int n = 0; n < 4; n++)
#pragma unroll
                for (int r = 0; r < 4; r++) {
                    size_t rr = row0 + m * 16 + g * 4 + r;
                    int cc = col0 + n * 16 + lr;
                    float o = acc[m][n][r];
                    if (RESID) o += b2f(resid[rr * 1024 + cc]);
                    C[rr * (size_t)ldc + cc] = o;
                }
    }
}

// ---------------------------------------------------------------------------
// Attention: one block per (b, head-group-of-4); wave w handles head hg*4+w.
// qkv layout per row m=b*28+s: [q 0..1023 | k 1024..2047 | v 2048..3071].
// S=28 padded to 32 (pad rows zeroed; pad cols masked). ctx overwrites q region.
// grid 8192, block 256.
// ---------------------------------------------------------------------------
__global__ __launch_bounds__(256) void attn_kernel(u16* __restrict__ qkv) {
    __shared__ u16 sq[32][264];      // q rows x 256 cols (4 heads) + pad
    __shared__ u16 sk[32][264];
    __shared__ u16 svt[256][40];     // v transposed: [head-local d (256)][j 32 + pad]
    __shared__ u16 sp[4][32][40];    // P per wave: [i 32][j 32 + pad]

    int t = threadIdx.x;
    int b = blockIdx.x >> 2, hg = blockIdx.x & 3;
    u16* base = qkv + (size_t)b * 28 * 3072 + hg * 256;

    {
        int rhalf = t >> 7;          // 0..1
        int c2 = (t & 127) * 2;      // even col in [0,256)
        for (int it = 0; it < 14; ++it) {
            int row = it * 2 + rhalf;
            const u16* src = base + (size_t)row * 3072;
            unsigned int qv = *(const unsigned int*)(src + c2);
            *(unsigned int*)&sq[row][c2] = qv;
            unsigned int kv = *(const unsigned int*)(src + 1024 + c2);
            *(unsigned int*)&sk[row][c2] = kv;
            unsigned int vv = *(const unsigned int*)(src + 2048 + c2);
            svt[c2][row] = (u16)(vv & 0xffffu);
            svt[c2 + 1][row] = (u16)(vv >> 16);
        }
#pragma unroll
        for (int r = 28; r < 32; ++r) {
            sq[r][t] = 0;
            sk[r][t] = 0;
        }
#pragma unroll
        for (int j = 28; j < 32; ++j) svt[t][j] = 0;
    }
    __syncthreads();

    int w = t >> 6, l = t & 63, g = l >> 4, lr = l & 15;
    int head = hg * 4 + w;

    // ---- scores = q @ k^T  (2 i-tiles x 2 j-tiles, K=64 in two 32-chunks) ----
    f32x4 acc[2][2];
#pragma unroll
    for (int a = 0; a < 2; a++)
#pragma unroll
        for (int c = 0; c < 2; c++) acc[a][c] = {0.f, 0.f, 0.f, 0.f};
#pragma unroll
    for (int c = 0; c < 2; c++) {
        int d0 = w * 64 + c * 32 + g * 8;
        bf16x8 a0 = *(const bf16x8*)&sq[lr][d0];
        bf16x8 a1 = *(const bf16x8*)&sq[16 + lr][d0];
        bf16x8 b0 = *(const bf16x8*)&sk[lr][d0];
        bf16x8 b1 = *(const bf16x8*)&sk[16 + lr][d0];
        acc[0][0] = __builtin_amdgcn_mfma_f32_16x16x32_bf16(a0, b0, acc[0][0], 0, 0, 0);
        acc[0][1] = __builtin_amdgcn_mfma_f32_16x16x32_bf16(a0, b1, acc[0][1], 0, 0, 0);
        acc[1][0] = __builtin_amdgcn_mfma_f32_16x16x32_bf16(a1, b0, acc[1][0], 0, 0, 0);
        acc[1][1] = __builtin_amdgcn_mfma_f32_16x16x32_bf16(a1, b1, acc[1][1], 0, 0, 0);
    }

    // ---- bias + softmax (rows distributed as C-layout: row=g*4+r, col=lane&15) ----
    float slope = exp2f(-0.5f * (float)(head + 1));
    int j0 = lr, j1 = 16 + lr;
    int j0m = j0 % 14, j0d = j0 / 14;
    int j1m = j1 % 14, j1d = j1 / 14;
#pragma unroll
    for (int it = 0; it < 2; ++it) {
#pragma unroll
        for (int r = 0; r < 4; ++r) {
            int i = it * 16 + g * 4 + r;
            int im = i % 14, id = i / 14;
            float s0 = acc[it][0][r] + slope * (float)(iabs(im - j0m) + iabs(id - j0d));
            float s1 = (j1 < 28)
                           ? acc[it][1][r] + slope * (float)(iabs(im - j1m) + iabs(id - j1d))
                           : -1e30f;
            float mx = fmaxf(s0, s1);
#pragma unroll
            for (int off = 1; off < 16; off <<= 1) mx = fmaxf(mx, __shfl_xor(mx, off));
            float e0 = __expf(s0 - mx), e1 = __expf(s1 - mx);
            float sm = e0 + e1;
#pragma unroll
            for (int off = 1; off < 16; off <<= 1) sm += __shfl_xor(sm, off);
            float inv = 1.f / sm;
            sp[w][i][lr] = f2b(e0 * inv);
            sp[w][i][16 + lr] = f2b(e1 * inv);
        }
    }
    __syncthreads();

    // ---- ctx = P @ v  (2 i-tiles x 4 d-tiles, K=32 = full padded j) ----
    bf16x8 pa0 = *(const bf16x8*)&sp[w][lr][g * 8];
    bf16x8 pa1 = *(const bf16x8*)&sp[w][16 + lr][g * 8];
    f32x4 o[2][4];
#pragma unroll
    for (int a = 0; a < 2; a++)
#pragma unroll
        for (int d = 0; d < 4; d++) o[a][d] = {0.f, 0.f, 0.f, 0.f};
#pragma unroll
    for (int dt = 0; dt < 4; ++dt) {
        bf16x8 bv = *(const bf16x8*)&svt[w * 64 + dt * 16 + lr][g * 8];
        o[0][dt] = __builtin_amdgcn_mfma_f32_16x16x32_bf16(pa0, bv, o[0][dt], 0, 0, 0);
        o[1][dt] = __builtin_amdgcn_mfma_f32_16x16x32_bf16(pa1, bv, o[1][dt], 0, 0, 0);
    }
#pragma unroll
    for (int it = 0; it < 2; ++it)
#pragma unroll
        for (int dt = 0; dt < 4; ++dt)
#pragma unroll
            for (int r = 0; r < 4; ++r) {
                int i = it * 16 + g * 4 + r;
                if (i < 28) {
                    size_t off = (size_t)(b * 28 + i) * 3072 + hg * 256 + w * 64 + dt * 16 + lr;
                    qkv[off] = f2b(o[it][dt][r]);
                }
            }
}

// ---------------------------------------------------------------------------
extern "C" void kernel_launch(void* const* d_in, const int* in_sizes, int n_in,
                              void* d_out, int out_size, void* d_ws, size_t ws_size,
                              hipStream_t stream) {
    (void)in_sizes; (void)n_in; (void)out_size; (void)ws_size;
    const float* hidden = (const float*)d_in[0];
    const float* wq = (const float*)d_in[1];
    const float* wk = (const float*)d_in[2];
    const float* wv = (const float*)d_in[3];
    const float* wo = (const float*)d_in[4];
    const float* gamma = (const float*)d_in[5];
    const float* beta = (const float*)d_in[6];
    float* out = (float*)d_out;

    char* ws = (char*)d_ws;
    u16* h = (u16*)ws;                                          // 117,440,512 B
    u16* qkv = (u16*)(ws + 117440512);                          // 352,321,536 B
    u16* wqkvt = (u16*)(ws + 117440512 + 352321536);            //   6,291,456 B
    u16* wot = (u16*)(ws + 117440512 + 352321536 + 6291456);    //   2,097,152 B

    wconv_kernel<<<dim3(32, 32, 4), 256, 0, stream>>>(wq, wk, wv, wo, wqkvt, wot);
    ln_kernel<<<14336, 256, 0, stream>>>(hidden, gamma, beta, h);
    gemm_bt<1, 0><<<448 * 24, 256, 0, stream>>>(h, wqkvt, qkv, nullptr, 1024, 3072);
    attn_kernel<<<8192, 256, 0, stream>>>(qkv);
    gemm_bt<0, 1><<<448 * 8, 256, 0, stream>>>(qkv, wot, out, h, 3072, 1024);
}